// Round 8
// baseline (285.607 us; speedup 1.0000x reference)
//
#include <hip/hip_runtime.h>

// DIM=256 H=8 HD=32 W=64 N=8192 nw=128
// xyz: T=40, off=20, hi=39, R=120 ; rgb: T=32, off=16, hi=31, R=96
// table element ((c*T+t)*8+h)*32+d == r*256 + h*32 + d, r=c*T+t

typedef __attribute__((ext_vector_type(8))) short short8;
typedef __attribute__((ext_vector_type(4))) float f32x4;

__device__ __forceinline__ unsigned short f2bf(float f) {
    union { float f; unsigned int u; } v; v.f = f;
    unsigned int r = v.u + 0x7FFFu + ((v.u >> 16) & 1u);
    return (unsigned short)(r >> 16);
}
__device__ __forceinline__ float bf2f(ushort u) {
    union { unsigned int u; float f; } v; v.u = ((unsigned int)u) << 16;
    return v.f;
}

// ---------------------------------------------------------------------------
// Cast prepass: fp32 -> bf16 for feats, qkv_w, proj_w, 6 tables.
// ---------------------------------------------------------------------------
__global__ __launch_bounds__(256) void k_cast(
    const float* __restrict__ s0, const float* __restrict__ s1,
    const float* __restrict__ s2, const float* __restrict__ s3,
    const float* __restrict__ s4, const float* __restrict__ s5,
    const float* __restrict__ s6, const float* __restrict__ s7,
    const float* __restrict__ s8, ushort* __restrict__ dst)
{
    unsigned g = blockIdx.x * 256 + threadIdx.x;   // float4 index, < 631296
    const float* src;
    unsigned base;
    if      (g < 524288u) { src = s0; base = 0; }
    else if (g < 573440u) { src = s1; base = 524288u; }
    else if (g < 589824u) { src = s2; base = 573440u; }
    else if (g < 597504u) { src = s3; base = 589824u; }
    else if (g < 605184u) { src = s4; base = 597504u; }
    else if (g < 612864u) { src = s5; base = 605184u; }
    else if (g < 619008u) { src = s6; base = 612864u; }
    else if (g < 625152u) { src = s7; base = 619008u; }
    else                  { src = s8; base = 625152u; }
    float4 v = *(const float4*)(src + (size_t)(g - base) * 4);
    ushort4 o;
    o.x = f2bf(v.x); o.y = f2bf(v.y); o.z = f2bf(v.z); o.w = f2bf(v.w);
    *(ushort4*)(dst + (size_t)g * 4) = o;
}

// ---------------------------------------------------------------------------
// QKV GEMM (bf16 MFMA): qkv = feats @ qkv_w^T + b -> q/k/v bf16 [nw][H][W][HD]
// ---------------------------------------------------------------------------
__global__ __launch_bounds__(256) void k_qkv(
    const ushort* __restrict__ A, const ushort* __restrict__ B,
    const float* __restrict__ bias,
    ushort* __restrict__ qb, ushort* __restrict__ kb, ushort* __restrict__ vb)
{
    __shared__ __align__(16) ushort a_s[128 * 72];
    __shared__ __align__(16) ushort b_s[64 * 72];
    const int tid = threadIdx.x;
    const int m0 = blockIdx.y * 128;
    const int n0 = blockIdx.x * 64;
    const int w = tid >> 6, wm = w >> 1, wn = w & 1;
    const int l4 = tid & 15, quad = (tid >> 4) & 3;
    f32x4 acc[4][2];
#pragma unroll
    for (int mt = 0; mt < 4; ++mt)
#pragma unroll
        for (int nt = 0; nt < 2; ++nt) acc[mt][nt] = (f32x4){0.f, 0.f, 0.f, 0.f};

    for (int k0 = 0; k0 < 256; k0 += 64) {
#pragma unroll
        for (int l = 0; l < 4; ++l) {
            int e = tid + l * 256;
            int row = e >> 3, kq = e & 7;
            *(uint4*)&a_s[row * 72 + kq * 8] =
                *(const uint4*)(A + (size_t)(m0 + row) * 256 + k0 + kq * 8);
        }
#pragma unroll
        for (int l = 0; l < 2; ++l) {
            int e = tid + l * 256;
            int row = e >> 3, kq = e & 7;
            *(uint4*)&b_s[row * 72 + kq * 8] =
                *(const uint4*)(B + (size_t)(n0 + row) * 256 + k0 + kq * 8);
        }
        __syncthreads();
#pragma unroll
        for (int kh = 0; kh < 2; ++kh) {
            short8 bf0 = *(const short8*)&b_s[(wn * 32 + l4) * 72 + kh * 32 + quad * 8];
            short8 bf1 = *(const short8*)&b_s[(wn * 32 + 16 + l4) * 72 + kh * 32 + quad * 8];
#pragma unroll
            for (int mt = 0; mt < 4; ++mt) {
                short8 af = *(const short8*)&a_s[(wm * 64 + mt * 16 + l4) * 72 + kh * 32 + quad * 8];
                acc[mt][0] = __builtin_amdgcn_mfma_f32_16x16x32_bf16(af, bf0, acc[mt][0], 0, 0, 0);
                acc[mt][1] = __builtin_amdgcn_mfma_f32_16x16x32_bf16(af, bf1, acc[mt][1], 0, 0, 0);
            }
        }
        __syncthreads();
    }
#pragma unroll
    for (int nt = 0; nt < 2; ++nt) {
        int c = n0 + wn * 32 + nt * 16 + l4;
        float bv = bias[c];
        int s = c >> 8, rem = c & 255, h = rem >> 5, d = rem & 31;
        ushort* dst = (s == 0) ? qb : ((s == 1) ? kb : vb);
        float mul = (s == 0) ? 0.17677669529663687f : 1.0f;
#pragma unroll
        for (int mt = 0; mt < 4; ++mt) {
            int mbase = m0 + wm * 64 + mt * 16 + quad * 4;
#pragma unroll
            for (int reg = 0; reg < 4; ++reg) {
                int m = mbase + reg;
                int nw = m >> 6, ii = m & 63;
                dst[((size_t)((nw * 8 + h) * 64 + ii)) * 32 + d] = f2bf((acc[mt][nt][reg] + bv) * mul);
            }
        }
    }
}

// ---------------------------------------------------------------------------
// MFMA attention per (window, head), merged xyz+rgb phases (10 barriers).
// LDS map (ushort el), total 30,336 el = 60,672 B (2 blocks/CU):
//   Phase A: q_s[64][40]@0, k_s[64][40]@2560, tbl[224][40]@5120 (xyz rows
//   0..119, zeros 120..127, rgb rows 128..223), cwf f32[64][6]@14080,
//   dbufA bf16[64][218]@14848 (dk/dq: xyz cols 0..119, rgb 120..215).
//   Phase B overlays: attn_s[64][72]@0, v_t[32][72]@4608, vtbl[32][136]@6912,
//   bins f32[64][121]@14848 (over dbufA).
// No min-waves in __launch_bounds__ (rounds 4-6: any min-waves pins VGPRs to
// a quantum and spills ~100s of MB to scratch).
// ---------------------------------------------------------------------------
__global__ __launch_bounds__(256) void k_attn(
    const ushort* __restrict__ qb, const ushort* __restrict__ kb, const ushort* __restrict__ vb,
    const float* __restrict__ nco,
    const ushort* __restrict__ qxt, const ushort* __restrict__ kxt, const ushort* __restrict__ vxt,
    const ushort* __restrict__ qrt, const ushort* __restrict__ krt, const ushort* __restrict__ vrt,
    ushort* __restrict__ aout)
{
    __shared__ __align__(16) ushort L[30336];
    ushort* q_s   = L;                       // [64][40]
    ushort* k_s   = L + 2560;                // [64][40]
    ushort* tbl   = L + 5120;                // [224][40]
    float*  cwf   = (float*)(L + 14080);     // [64][6], alive whole kernel
    ushort* dbufA = L + 14848;               // bf16 [64][218]
    ushort* attn_s = L;                      // [64][72]
    ushort* v_t    = L + 4608;               // [32][72]
    ushort* vtbl   = L + 6912;               // [32][136]
    float*  bins   = (float*)(L + 14848);    // [64][121]

    const int tid = threadIdx.x;
    const int n = blockIdx.x >> 3;
    const int h = blockIdx.x & 7;
    const int w = tid >> 6;
    const int l4 = tid & 15;
    const int quad = (tid >> 4) & 3;

    const size_t base = (size_t)((n * 8 + h) * 64) * 32;

    // ---- step 1: stage q, k, coords, combined k-tables ----
    {
        int row = tid >> 2, part = tid & 3;
        *(uint4*)&q_s[row * 40 + part * 8] = *(const uint4*)(qb + base + tid * 8);
        *(uint4*)&k_s[row * 40 + part * 8] = *(const uint4*)(kb + base + tid * 8);
    }
    if (tid < 64) {
        const float* cp = nco + (size_t)(n * 64 + tid) * 6;
        cwf[tid * 6 + 0] = cp[0] * 4.f; cwf[tid * 6 + 1] = cp[1] * 4.f;
        cwf[tid * 6 + 2] = cp[2] * 4.f; cwf[tid * 6 + 3] = cp[3] * 8.f;
        cwf[tid * 6 + 4] = cp[4] * 8.f; cwf[tid * 6 + 5] = cp[5] * 8.f;
    }

    auto stageTblPair = [&](const ushort* tx, const ushort* tr) {
        // xyz: 120 rows x 4 chunks = 480, rgb: 96 x 4 = 384 -> 864 chunks
        for (int e = tid; e < 864; e += 256) {
            const ushort* src; ushort* dp;
            if (e < 480) {
                int row = e >> 2, c = e & 3;
                src = tx + (size_t)row * 256 + c * 8;
                dp = &tbl[row * 40 + c * 8];
            } else {
                int e2 = e - 480;
                int row = e2 >> 2, c = e2 & 3;
                src = tr + (size_t)row * 256 + c * 8;
                dp = &tbl[(128 + row) * 40 + c * 8];
            }
            *(uint4*)dp = *(const uint4*)src;
        }
        if (tid < 32) {   // zero rows 120..127
            uint4 z = {0u, 0u, 0u, 0u};
            *(uint4*)&tbl[(120 + (tid >> 2)) * 40 + (tid & 3) * 8] = z;
        }
    };
    auto stageVtbl = [&](const ushort* tbg, int R) {
        int r = tid >> 1, half = tid & 1;
        if (r < R) {
            const ushort* src = tbg + (size_t)r * 256 + half * 16;
            uint4 p0 = *(const uint4*)src, p1 = *(const uint4*)(src + 8);
            const ushort* u0 = (const ushort*)&p0;
            const ushort* u1 = (const ushort*)&p1;
#pragma unroll
            for (int ii = 0; ii < 8; ++ii) {
                vtbl[(half * 16 + ii) * 136 + r] = u0[ii];
                vtbl[(half * 16 + 8 + ii) * 136 + r] = u1[ii];
            }
        }
        int span = 128 - R;
        for (int e = tid; e < 32 * span; e += 256) {
            int d = e / span, rr = e - d * span;
            vtbl[d * 136 + R + rr] = 0;
        }
    };
    auto stageVt = [&]() {
        int j = tid >> 2, d0 = (tid & 3) * 8;
        uint4 pk = *(const uint4*)(vb + base + tid * 8);
        const ushort* u = (const ushort*)&pk;
#pragma unroll
        for (int ii = 0; ii < 8; ++ii) v_t[(d0 + ii) * 72 + j] = u[ii];
    };

    // merged tgemm: dX[row][col] over xyz (cols 0..119) + rgb (cols 120..215)
    auto tgemm = [&](const ushort* a_s) {
        short8 af = *(const short8*)&a_s[(w * 16 + l4) * 40 + quad * 8];
#pragma unroll
        for (int tt = 0; tt < 14; ++tt) {
            short8 bf = *(const short8*)&tbl[(tt * 16 + l4) * 40 + quad * 8];
            f32x4 a = {0.f, 0.f, 0.f, 0.f};
            a = __builtin_amdgcn_mfma_f32_16x16x32_bf16(af, bf, a, 0, 0, 0);
            int rb = w * 16 + quad * 4;
            int col = (tt < 8) ? (tt * 16 + l4) : (120 + (tt - 8) * 16 + l4);
            if (tt < 8 && col >= 120) continue;   // xyz pad rows -> dropped
            dbufA[(rb + 0) * 218 + col] = f2bf(a[0]);
            dbufA[(rb + 1) * 218 + col] = f2bf(a[1]);
            dbufA[(rb + 2) * 218 + col] = f2bf(a[2]);
            dbufA[(rb + 3) * 218 + col] = f2bf(a[3]);
        }
    };

    stageTblPair(kxt + h * 32, krt + h * 32);
    __syncthreads();

    // ---- step 2: idx precompute, QK, tgemm_k ----
    // idx strictly register-resident: constant-indexed, never address-taken.
    int idxX[4][4], idxR[4][4];   // [tt][reg], packed t0|t1<<8|t2<<16
#pragma unroll
    for (int tt = 0; tt < 4; ++tt) {
        int j = tt * 16 + l4;
        float cj0 = cwf[j * 6 + 0], cj1 = cwf[j * 6 + 1], cj2 = cwf[j * 6 + 2];
        float cj3 = cwf[j * 6 + 3], cj4 = cwf[j * 6 + 4], cj5 = cwf[j * 6 + 5];
#pragma unroll
        for (int reg = 0; reg < 4; ++reg) {
            int i = w * 16 + quad * 4 + reg;
            int x0 = min(max((int)floorf(cwf[i * 6 + 0] - cj0) + 20, 0), 39);
            int x1 = min(max((int)floorf(cwf[i * 6 + 1] - cj1) + 20, 0), 39);
            int x2 = min(max((int)floorf(cwf[i * 6 + 2] - cj2) + 20, 0), 39);
            idxX[tt][reg] = x0 | (x1 << 8) | (x2 << 16);
            int r0 = min(max((int)floorf(cwf[i * 6 + 3] - cj3) + 16, 0), 31);
            int r1 = min(max((int)floorf(cwf[i * 6 + 4] - cj4) + 16, 0), 31);
            int r2 = min(max((int)floorf(cwf[i * 6 + 5] - cj5) + 16, 0), 31);
            idxR[tt][reg] = r0 | (r1 << 8) | (r2 << 16);
        }
    }

    float lg[4][4];   // [tt][reg]: row i = w*16+quad*4+reg, col j = tt*16+l4
    {
        short8 aq = *(const short8*)&q_s[(w * 16 + l4) * 40 + quad * 8];
#pragma unroll
        for (int tt = 0; tt < 4; ++tt) {
            short8 bk = *(const short8*)&k_s[(tt * 16 + l4) * 40 + quad * 8];
            f32x4 r = {0.f, 0.f, 0.f, 0.f};
            r = __builtin_amdgcn_mfma_f32_16x16x32_bf16(aq, bk, r, 0, 0, 0);
            lg[tt][0] = r[0]; lg[tt][1] = r[1]; lg[tt][2] = r[2]; lg[tt][3] = r[3];
        }
    }
    tgemm(k_s);
    __syncthreads();

    // ---- step 3: merged gather (k-side), stage q-tables ----
    auto gatherAll = [&](bool useJ) {
#pragma unroll
        for (int tt = 0; tt < 4; ++tt) {
#pragma unroll
            for (int reg = 0; reg < 4; ++reg) {
                int pX = idxX[tt][reg], pR = idxR[tt][reg];
                int b = (useJ ? (tt * 16 + l4) : (w * 16 + quad * 4 + reg)) * 218;
                lg[tt][reg] += bf2f(dbufA[b + (pX & 255)])
                             + bf2f(dbufA[b + 40 + ((pX >> 8) & 255)])
                             + bf2f(dbufA[b + 80 + (pX >> 16)])
                             + bf2f(dbufA[b + 120 + (pR & 255)])
                             + bf2f(dbufA[b + 152 + ((pR >> 8) & 255)])
                             + bf2f(dbufA[b + 184 + (pR >> 16)]);
            }
        }
    };
    gatherAll(true);
    stageTblPair(qxt + h * 32, qrt + h * 32);
    __syncthreads();

    // ---- step 4: tgemm_q ----
    tgemm(q_s);
    __syncthreads();

    // ---- step 5: merged gather (q-side), stage vtbl_x + v_t ----
    gatherAll(false);
    stageVtbl(vxt + h * 32, 120);
    stageVt();
    __syncthreads();

    // ---- step 6: softmax, attn write, zero bins ----
#pragma unroll
    for (int reg = 0; reg < 4; ++reg) {
        float m = fmaxf(fmaxf(lg[0][reg], lg[1][reg]), fmaxf(lg[2][reg], lg[3][reg]));
        m = fmaxf(m, __shfl_xor(m, 1));
        m = fmaxf(m, __shfl_xor(m, 2));
        m = fmaxf(m, __shfl_xor(m, 4));
        m = fmaxf(m, __shfl_xor(m, 8));
        float s = 0.f;
#pragma unroll
        for (int tt = 0; tt < 4; ++tt) { lg[tt][reg] = __expf(lg[tt][reg] - m); s += lg[tt][reg]; }
        s += __shfl_xor(s, 1); s += __shfl_xor(s, 2);
        s += __shfl_xor(s, 4); s += __shfl_xor(s, 8);
        float inv = 1.f / s;
#pragma unroll
        for (int tt = 0; tt < 4; ++tt) lg[tt][reg] *= inv;
    }
#pragma unroll
    for (int tt = 0; tt < 4; ++tt)
#pragma unroll
        for (int reg = 0; reg < 4; ++reg)
            attn_s[(w * 16 + quad * 4 + reg) * 72 + tt * 16 + l4] = f2bf(lg[tt][reg]);

    auto zeroBins = [&]() {
        float4 z = {0.f, 0.f, 0.f, 0.f};
        for (int e = tid * 4; e < 64 * 121; e += 1024) *(float4*)&bins[e] = z;
    };
    zeroBins();
    __syncthreads();

    // ---- step 7: scatter xyz + AV ----
    auto scatterX = [&]() {
#pragma unroll
        for (int reg = 0; reg < 4; ++reg) {
            float* bi = &bins[(w * 16 + quad * 4 + reg) * 121];
#pragma unroll
            for (int tt = 0; tt < 4; ++tt) {
                int p = idxX[tt][reg];
                float a = lg[tt][reg];
                atomicAdd(bi + (p & 255), a);
                atomicAdd(bi + 40 + ((p >> 8) & 255), a);
                atomicAdd(bi + 80 + (p >> 16), a);
            }
        }
    };
    auto scatterR = [&]() {
#pragma unroll
        for (int reg = 0; reg < 4; ++reg) {
            float* bi = &bins[(w * 16 + quad * 4 + reg) * 121];
#pragma unroll
            for (int tt = 0; tt < 4; ++tt) {
                int p = idxR[tt][reg];
                float a = lg[tt][reg];
                atomicAdd(bi + (p & 255), a);
                atomicAdd(bi + 32 + ((p >> 8) & 255), a);
                atomicAdd(bi + 64 + (p >> 16), a);
            }
        }
    };
    scatterX();
    f32x4 acc0 = {0.f, 0.f, 0.f, 0.f}, acc1 = {0.f, 0.f, 0.f, 0.f};
#pragma unroll
    for (int s = 0; s < 2; ++s) {
        short8 af = *(const short8*)&attn_s[(w * 16 + l4) * 72 + s * 32 + quad * 8];
        short8 b0 = *(const short8*)&v_t[l4 * 72 + s * 32 + quad * 8];
        short8 b1 = *(const short8*)&v_t[(16 + l4) * 72 + s * 32 + quad * 8];
        acc0 = __builtin_amdgcn_mfma_f32_16x16x32_bf16(af, b0, acc0, 0, 0, 0);
        acc1 = __builtin_amdgcn_mfma_f32_16x16x32_bf16(af, b1, acc1, 0, 0, 0);
    }
    __syncthreads();

    // ---- step 8: value-bias xyz ----
    auto atgemm = [&](int Rlim) {
#pragma unroll
        for (int s = 0; s < 4; ++s) {
            int koff = s * 32 + quad * 8;
            short8 af = {0, 0, 0, 0, 0, 0, 0, 0};
            if (koff < Rlim) {
                const float* ap = &bins[(w * 16 + l4) * 121 + koff];
#pragma unroll
                for (int ii = 0; ii < 8; ++ii) af[ii] = (short)f2bf(ap[ii]);
            }
            short8 b0 = *(const short8*)&vtbl[l4 * 136 + koff];
            short8 b1 = *(const short8*)&vtbl[(16 + l4) * 136 + koff];
            acc0 = __builtin_amdgcn_mfma_f32_16x16x32_bf16(af, b0, acc0, 0, 0, 0);
            acc1 = __builtin_amdgcn_mfma_f32_16x16x32_bf16(af, b1, acc1, 0, 0, 0);
        }
    };
    atgemm(120);
    __syncthreads();

    // ---- step 9: re-zero bins, stage vtbl_r ----
    zeroBins();
    stageVtbl(vrt + h * 32, 96);
    __syncthreads();

    // ---- step 10: scatter rgb ----
    scatterR();
    __syncthreads();

    // ---- step 11: value-bias rgb + epilogue ----
    atgemm(96);
    {
        ushort* op = aout + (size_t)(n * 64 + w * 16 + quad * 4) * 256 + h * 32;
#pragma unroll
        for (int reg = 0; reg < 4; ++reg) {
            op[reg * 256 + l4] = f2bf(acc0[reg]);
            op[reg * 256 + 16 + l4] = f2bf(acc1[reg]);
        }
    }
}

// ---------------------------------------------------------------------------
// Proj GEMM (bf16 MFMA): out = ao @ proj_w^T + proj_b (fp32 out)
// ---------------------------------------------------------------------------
__global__ __launch_bounds__(256) void k_proj(
    const ushort* __restrict__ A, const ushort* __restrict__ B,
    const float* __restrict__ bias, float* __restrict__ out)
{
    __shared__ __align__(16) ushort a_s[128 * 72];
    __shared__ __align__(16) ushort b_s[64 * 72];
    const int tid = threadIdx.x;
    const int m0 = blockIdx.y * 128;
    const int n0 = blockIdx.x * 64;
    const int w = tid >> 6, wm = w >> 1, wn = w & 1;
    const int l4 = tid & 15, quad = (tid >> 4) & 3;
    f32x4 acc[4][2];
#pragma unroll
    for (int mt = 0; mt < 4; ++mt)
#pragma unroll
        for (int nt = 0; nt < 2; ++nt) acc[mt][nt] = (f32x4){0.f, 0.f, 0.f, 0.f};

    for (int k0 = 0; k0 < 256; k0 += 64) {
#pragma unroll
        for (int l = 0; l < 4; ++l) {
            int e = tid + l * 256;
            int row = e >> 3, kq = e & 7;
            *(uint4*)&a_s[row * 72 + kq * 8] =
                *(const uint4*)(A + (size_t)(m0 + row) * 256 + k0 + kq * 8);
        }
#pragma unroll
        for (int l = 0; l < 2; ++l) {
            int e = tid + l * 256;
            int row = e >> 3, kq = e & 7;
            *(uint4*)&b_s[row * 72 + kq * 8] =
                *(const uint4*)(B + (size_t)(n0 + row) * 256 + k0 + kq * 8);
        }
        __syncthreads();
#pragma unroll
        for (int kh = 0; kh < 2; ++kh) {
            short8 bf0 = *(const short8*)&b_s[(wn * 32 + l4) * 72 + kh * 32 + quad * 8];
            short8 bf1 = *(const short8*)&b_s[(wn * 32 + 16 + l4) * 72 + kh * 32 + quad * 8];
#pragma unroll
            for (int mt = 0; mt < 4; ++mt) {
                short8 af = *(const short8*)&a_s[(wm * 64 + mt * 16 + l4) * 72 + kh * 32 + quad * 8];
                acc[mt][0] = __builtin_amdgcn_mfma_f32_16x16x32_bf16(af, bf0, acc[mt][0], 0, 0, 0);
                acc[mt][1] = __builtin_amdgcn_mfma_f32_16x16x32_bf16(af, bf1, acc[mt][1], 0, 0, 0);
            }
        }
        __syncthreads();
    }
#pragma unroll
    for (int nt = 0; nt < 2; ++nt) {
        int c = n0 + wn * 32 + nt * 16 + l4;
        float bv = bias[c];
#pragma unroll
        for (int mt = 0; mt < 4; ++mt) {
            int mbase = m0 + wm * 64 + mt * 16 + quad * 4;
#pragma unroll
            for (int reg = 0; reg < 4; ++reg)
                out[(size_t)(mbase + reg) * 256 + c] = acc[mt][nt][reg] + bv;
        }
    }
}

extern "C" void kernel_launch(void* const* d_in, const int* in_sizes, int n_in,
                              void* d_out, int out_size, void* d_ws, size_t ws_size,
                              hipStream_t stream)
{
    const float* feats = (const float*)d_in[0];
    const float* nco   = (const float*)d_in[1];
    const float* qkvw  = (const float*)d_in[2];
    const float* qkvb  = (const float*)d_in[3];
    const float* qxt   = (const float*)d_in[4];
    const float* kxt   = (const float*)d_in[5];
    const float* vxt   = (const float*)d_in[6];
    const float* qrt   = (const float*)d_in[7];
    const float* krt   = (const float*)d_in[8];
    const float* vrt   = (const float*)d_in[9];
    const float* pw    = (const float*)d_in[10];
    const float* pb    = (const float*)d_in[11];
    float* out = (float*)d_out;

    ushort* qb  = (ushort*)d_ws;                       // [128][8][64][32]
    ushort* kb  = qb + (size_t)2097152;
    ushort* vb  = kb + (size_t)2097152;
    ushort* aob = vb + (size_t)2097152;                // [8192][256] bf16
    ushort* cst = aob + (size_t)2097152;               // bf16 cast region
    ushort* featsB = cst;                              // 2,097,152 el
    ushort* qkvwB  = cst + (size_t)2097152;            //   196,608 el
    ushort* projwB = cst + (size_t)2293760;            //    65,536 el
    ushort* qxtB   = cst + (size_t)2359296;            //    30,720 el
    ushort* kxtB   = cst + (size_t)2390016;
    ushort* vxtB   = cst + (size_t)2420736;
    ushort* qrtB   = cst + (size_t)2451456;            //    24,576 el
    ushort* krtB   = cst + (size_t)2476032;
    ushort* vrtB   = cst + (size_t)2500608;            // end 2,525,184 el

    k_cast<<<dim3(2466), 256, 0, stream>>>(feats, qkvw, pw, qxt, kxt, vxt, qrt, krt, vrt, cst);
    k_qkv<<<dim3(12, 64), 256, 0, stream>>>(featsB, qkvwB, qkvb, qb, kb, vb);
    k_attn<<<dim3(1024), 256, 0, stream>>>(qb, kb, vb, nco, qxtB, kxtB, vxtB, qrtB, krtB, vrtB, aob);
    k_proj<<<dim3(4, 64), 256, 0, stream>>>(aob, projwB, pb, out);
}

// Round 9
// 281.496 us; speedup vs baseline: 1.0146x; 1.0146x over previous
//
#include <hip/hip_runtime.h>

// DIM=256 H=8 HD=32 W=64 N=8192 nw=128
// xyz: T=40, off=20, hi=39, R=120 (pad 128) ; rgb: T=32, off=16, hi=31, R=96
// table element ((c*T+t)*8+h)*32+d == r*256 + h*32 + d, r=c*T+t

typedef __attribute__((ext_vector_type(8))) short short8;
typedef __attribute__((ext_vector_type(4))) float f32x4;

__device__ __forceinline__ unsigned short f2bf(float f) {
    union { float f; unsigned int u; } v; v.f = f;
    unsigned int r = v.u + 0x7FFFu + ((v.u >> 16) & 1u);
    return (unsigned short)(r >> 16);
}

// ---------------------------------------------------------------------------
// QKV GEMM (bf16 MFMA), fp32 inputs cast inline during staging.
// qkv = feats @ qkv_w^T + b -> q/k/v bf16 [nw][H][W][HD], q pre-scaled.
// ---------------------------------------------------------------------------
__global__ __launch_bounds__(256) void k_qkv(
    const float* __restrict__ A, const float* __restrict__ B,
    const float* __restrict__ bias,
    ushort* __restrict__ qb, ushort* __restrict__ kb, ushort* __restrict__ vb)
{
    __shared__ __align__(16) ushort a_s[128 * 72];
    __shared__ __align__(16) ushort b_s[64 * 72];
    const int tid = threadIdx.x;
    const int m0 = blockIdx.y * 128;
    const int n0 = blockIdx.x * 64;
    const int w = tid >> 6, wm = w >> 1, wn = w & 1;
    const int l4 = tid & 15, quad = (tid >> 4) & 3;
    f32x4 acc[4][2];
#pragma unroll
    for (int mt = 0; mt < 4; ++mt)
#pragma unroll
        for (int nt = 0; nt < 2; ++nt) acc[mt][nt] = (f32x4){0.f, 0.f, 0.f, 0.f};

    for (int k0 = 0; k0 < 256; k0 += 64) {
#pragma unroll
        for (int l = 0; l < 4; ++l) {
            int e = tid + l * 256;
            int row = e >> 3, kq = e & 7;
            const float* ap = A + (size_t)(m0 + row) * 256 + k0 + kq * 8;
            float4 v0 = *(const float4*)ap, v1 = *(const float4*)(ap + 4);
            union { ushort u[8]; uint4 v; } pk;
            pk.u[0] = f2bf(v0.x); pk.u[1] = f2bf(v0.y); pk.u[2] = f2bf(v0.z); pk.u[3] = f2bf(v0.w);
            pk.u[4] = f2bf(v1.x); pk.u[5] = f2bf(v1.y); pk.u[6] = f2bf(v1.z); pk.u[7] = f2bf(v1.w);
            *(uint4*)&a_s[row * 72 + kq * 8] = pk.v;
        }
#pragma unroll
        for (int l = 0; l < 2; ++l) {
            int e = tid + l * 256;
            int row = e >> 3, kq = e & 7;
            const float* bp = B + (size_t)(n0 + row) * 256 + k0 + kq * 8;
            float4 v0 = *(const float4*)bp, v1 = *(const float4*)(bp + 4);
            union { ushort u[8]; uint4 v; } pk;
            pk.u[0] = f2bf(v0.x); pk.u[1] = f2bf(v0.y); pk.u[2] = f2bf(v0.z); pk.u[3] = f2bf(v0.w);
            pk.u[4] = f2bf(v1.x); pk.u[5] = f2bf(v1.y); pk.u[6] = f2bf(v1.z); pk.u[7] = f2bf(v1.w);
            *(uint4*)&b_s[row * 72 + kq * 8] = pk.v;
        }
        __syncthreads();
#pragma unroll
        for (int kh = 0; kh < 2; ++kh) {
            short8 bf0 = *(const short8*)&b_s[(wn * 32 + l4) * 72 + kh * 32 + quad * 8];
            short8 bf1 = *(const short8*)&b_s[(wn * 32 + 16 + l4) * 72 + kh * 32 + quad * 8];
#pragma unroll
            for (int mt = 0; mt < 4; ++mt) {
                short8 af = *(const short8*)&a_s[(wm * 64 + mt * 16 + l4) * 72 + kh * 32 + quad * 8];
                acc[mt][0] = __builtin_amdgcn_mfma_f32_16x16x32_bf16(af, bf0, acc[mt][0], 0, 0, 0);
                acc[mt][1] = __builtin_amdgcn_mfma_f32_16x16x32_bf16(af, bf1, acc[mt][1], 0, 0, 0);
            }
        }
        __syncthreads();
    }
#pragma unroll
    for (int nt = 0; nt < 2; ++nt) {
        int c = n0 + wn * 32 + nt * 16 + l4;
        float bv = bias[c];
        int s = c >> 8, rem = c & 255, h = rem >> 5, d = rem & 31;
        ushort* dst = (s == 0) ? qb : ((s == 1) ? kb : vb);
        float mul = (s == 0) ? 0.17677669529663687f : 1.0f;
#pragma unroll
        for (int mt = 0; mt < 4; ++mt) {
            int mbase = m0 + wm * 64 + mt * 16 + quad * 4;
#pragma unroll
            for (int reg = 0; reg < 4; ++reg) {
                int m = mbase + reg;
                int nw = m >> 6, ii = m & 63;
                dst[((size_t)((nw * 8 + h) * 64 + ii)) * 32 + d] = f2bf((acc[mt][nt][reg] + bv) * mul);
            }
        }
    }
}

// ---------------------------------------------------------------------------
// MFMA attention per (window, head) — round-7 phase structure (fastest base).
// A/B frag: [outer=lane&15][k=quad*8+j] ; C/D: col=lane&15, row=quad*4+reg.
// LDS: dbuf fp32 64x122 (31,232 B) + ushort union U (22,528 B) = 53,760 B
// -> 3 blocks/CU at LDS (161,280 <= 163,840).
// VGPR target <= 170 for 3 waves/SIMD (floor(512/VGPR)): round 7 landed 172
// (2 waves) — idxR is bit-packed (two 15-bit triples per int, 32->24 idx
// regs) to cross the threshold. NO min-waves bound (rounds 4-6: it pins
// VGPRs to a quantum and spills ~100 MB to scratch).
// Tables arrive fp32; staging converts inline (latency-bound, cvt is free).
// ---------------------------------------------------------------------------
#define DBS 122

__global__ __launch_bounds__(256) void k_attn(
    const ushort* __restrict__ qb, const ushort* __restrict__ kb, const ushort* __restrict__ vb,
    const float* __restrict__ nco,
    const float* __restrict__ qxt, const float* __restrict__ kxt, const float* __restrict__ vxt,
    const float* __restrict__ qrt, const float* __restrict__ krt, const float* __restrict__ vrt,
    ushort* __restrict__ aout)
{
    __shared__ __align__(16) float dbuf[64 * DBS];
    __shared__ __align__(16) ushort U[11264];
    // Phase A overlays:
    ushort* q_s  = U;              // [64][40]
    ushort* k_s  = U + 2560;       // [64][40]
    ushort* tbl  = U + 5120;       // [128][40]
    float*  cwf  = (float*)(U + 10240);  // [64][6], dead after idx precompute
    // Phase B overlays:
    ushort* attn_s = U;            // [64][72]
    ushort* v_t    = U + 4608;     // [32][72]
    ushort* vtbl   = U + 6912;     // [32][136]

    const int tid = threadIdx.x;
    const int n = blockIdx.x >> 3;
    const int h = blockIdx.x & 7;
    const int w = tid >> 6;
    const int l4 = tid & 15;
    const int quad = (tid >> 4) & 3;

    const size_t base = (size_t)((n * 8 + h) * 64) * 32;

    // ---- stage q, k, coords ----
    {
        int row = tid >> 2, part = tid & 3;
        *(uint4*)&q_s[row * 40 + part * 8] = *(const uint4*)(qb + base + tid * 8);
        *(uint4*)&k_s[row * 40 + part * 8] = *(const uint4*)(kb + base + tid * 8);
    }
    if (tid < 64) {
        const float* cp = nco + (size_t)(n * 64 + tid) * 6;
        cwf[tid * 6 + 0] = cp[0] * 4.f; cwf[tid * 6 + 1] = cp[1] * 4.f;
        cwf[tid * 6 + 2] = cp[2] * 4.f; cwf[tid * 6 + 3] = cp[3] * 8.f;
        cwf[tid * 6 + 4] = cp[4] * 8.f; cwf[tid * 6 + 5] = cp[5] * 8.f;
    }

    auto stageTbl = [&](const float* tbg, int R, int Rpad) {
        int r = tid >> 1, half = tid & 1;
        if (r < R) {
            const float* src = tbg + (size_t)r * 256 + half * 16;
            float4 f0 = *(const float4*)(src);
            float4 f1 = *(const float4*)(src + 4);
            float4 f2 = *(const float4*)(src + 8);
            float4 f3 = *(const float4*)(src + 12);
            union { ushort u[8]; uint4 v; } a, b;
            a.u[0] = f2bf(f0.x); a.u[1] = f2bf(f0.y); a.u[2] = f2bf(f0.z); a.u[3] = f2bf(f0.w);
            a.u[4] = f2bf(f1.x); a.u[5] = f2bf(f1.y); a.u[6] = f2bf(f1.z); a.u[7] = f2bf(f1.w);
            b.u[0] = f2bf(f2.x); b.u[1] = f2bf(f2.y); b.u[2] = f2bf(f2.z); b.u[3] = f2bf(f2.w);
            b.u[4] = f2bf(f3.x); b.u[5] = f2bf(f3.y); b.u[6] = f2bf(f3.z); b.u[7] = f2bf(f3.w);
            ushort* dp = &tbl[r * 40 + half * 16];
            *(uint4*)dp = a.v;
            *(uint4*)(dp + 8) = b.v;
        }
        for (int e = tid; e < (Rpad - R) * 40; e += 256) tbl[R * 40 + e] = 0;
    };
    auto stageVtbl = [&](const float* tbg, int R) {
        int r = tid >> 1, half = tid & 1;
        if (r < R) {
            const float* src = tbg + (size_t)r * 256 + half * 16;
#pragma unroll
            for (int ii = 0; ii < 16; ii += 4) {
                float4 f = *(const float4*)(src + ii);
                vtbl[(half * 16 + ii + 0) * 136 + r] = f2bf(f.x);
                vtbl[(half * 16 + ii + 1) * 136 + r] = f2bf(f.y);
                vtbl[(half * 16 + ii + 2) * 136 + r] = f2bf(f.z);
                vtbl[(half * 16 + ii + 3) * 136 + r] = f2bf(f.w);
            }
        }
        int span = 128 - R;
        for (int e = tid; e < 32 * span; e += 256) {
            int d = e / span, rr = e - d * span;
            vtbl[d * 136 + R + rr] = 0;
        }
    };
    auto stageVt = [&]() {
        int j = tid >> 2, d0 = (tid & 3) * 8;
        uint4 pk = *(const uint4*)(vb + base + tid * 8);
        const ushort* u = (const ushort*)&pk;
#pragma unroll
        for (int ii = 0; ii < 8; ++ii) v_t[(d0 + ii) * 72 + j] = u[ii];
    };

    auto tgemm = [&](const ushort* a_s, int NT, int maxc) {
        short8 af = *(const short8*)&a_s[(w * 16 + l4) * 40 + quad * 8];
        for (int tt = 0; tt < NT; ++tt) {
            short8 bf = *(const short8*)&tbl[(tt * 16 + l4) * 40 + quad * 8];
            f32x4 a = {0.f, 0.f, 0.f, 0.f};
            a = __builtin_amdgcn_mfma_f32_16x16x32_bf16(af, bf, a, 0, 0, 0);
            int col = tt * 16 + l4;
            int rb = w * 16 + quad * 4;
            if (col < maxc) {
                dbuf[(rb + 0) * DBS + col] = a[0];
                dbuf[(rb + 1) * DBS + col] = a[1];
                dbuf[(rb + 2) * DBS + col] = a[2];
                dbuf[(rb + 3) * DBS + col] = a[3];
            }
        }
    };

    stageTbl(kxt + h * 32, 120, 128);
    __syncthreads();

    // ---- precompute gather/scatter indices once ----
    // idxX: packed x0|x1<<8|x2<<16 per (tt,reg) — 16 ints.
    // idxR: two 15-bit triples (r0|r1<<5|r2<<10) per int — 8 ints total.
    // Strictly register-resident: constant-indexed, never address-taken.
    int idxX[4][4], idxRp[2][4];
#pragma unroll
    for (int tt = 0; tt < 4; ++tt) {
        int j = tt * 16 + l4;
        float cj0 = cwf[j * 6 + 0], cj1 = cwf[j * 6 + 1], cj2 = cwf[j * 6 + 2];
        float cj3 = cwf[j * 6 + 3], cj4 = cwf[j * 6 + 4], cj5 = cwf[j * 6 + 5];
#pragma unroll
        for (int reg = 0; reg < 4; ++reg) {
            int i = w * 16 + quad * 4 + reg;
            int x0 = min(max((int)floorf(cwf[i * 6 + 0] - cj0) + 20, 0), 39);
            int x1 = min(max((int)floorf(cwf[i * 6 + 1] - cj1) + 20, 0), 39);
            int x2 = min(max((int)floorf(cwf[i * 6 + 2] - cj2) + 20, 0), 39);
            idxX[tt][reg] = x0 | (x1 << 8) | (x2 << 16);
            int r0 = min(max((int)floorf(cwf[i * 6 + 3] - cj3) + 16, 0), 31);
            int r1 = min(max((int)floorf(cwf[i * 6 + 4] - cj4) + 16, 0), 31);
            int r2 = min(max((int)floorf(cwf[i * 6 + 5] - cj5) + 16, 0), 31);
            int tr = r0 | (r1 << 5) | (r2 << 10);
            if (tt < 2) idxRp[tt][reg] = tr;
            else        idxRp[tt - 2][reg] |= tr << 15;
        }
    }

    float lg[4][4];   // [tt][reg]: row i = w*16+quad*4+reg, col j = tt*16+l4

    auto gatherX = [&](bool useJ) {
#pragma unroll
        for (int tt = 0; tt < 4; ++tt) {
#pragma unroll
            for (int reg = 0; reg < 4; ++reg) {
                int p = idxX[tt][reg];
                int b = (useJ ? (tt * 16 + l4) : (w * 16 + quad * 4 + reg)) * DBS;
                lg[tt][reg] += dbuf[b + (p & 255)] + dbuf[b + 40 + ((p >> 8) & 255)]
                             + dbuf[b + 80 + (p >> 16)];
            }
        }
    };
    auto gatherR = [&](bool useJ) {
#pragma unroll
        for (int tt = 0; tt < 4; ++tt) {
#pragma unroll
            for (int reg = 0; reg < 4; ++reg) {
                int p = (idxRp[tt & 1][reg] >> ((tt >> 1) * 15)) & 0x7FFF;
                int b = (useJ ? (tt * 16 + l4) : (w * 16 + quad * 4 + reg)) * DBS;
                lg[tt][reg] += dbuf[b + (p & 31)] + dbuf[b + 32 + ((p >> 5) & 31)]
                             + dbuf[b + 64 + ((p >> 10) & 31)];
            }
        }
    };
    auto scatterX = [&]() {
#pragma unroll
        for (int reg = 0; reg < 4; ++reg) {
            float* bi = &dbuf[(w * 16 + quad * 4 + reg) * DBS];
#pragma unroll
            for (int tt = 0; tt < 4; ++tt) {
                int p = idxX[tt][reg];
                float a = lg[tt][reg];
                atomicAdd(bi + (p & 255), a);
                atomicAdd(bi + 40 + ((p >> 8) & 255), a);
                atomicAdd(bi + 80 + (p >> 16), a);
            }
        }
    };
    auto scatterR = [&]() {
#pragma unroll
        for (int reg = 0; reg < 4; ++reg) {
            float* bi = &dbuf[(w * 16 + quad * 4 + reg) * DBS];
#pragma unroll
            for (int tt = 0; tt < 4; ++tt) {
                int p = (idxRp[tt & 1][reg] >> ((tt >> 1) * 15)) & 0x7FFF;
                float a = lg[tt][reg];
                atomicAdd(bi + (p & 31), a);
                atomicAdd(bi + 32 + ((p >> 5) & 31), a);
                atomicAdd(bi + 64 + ((p >> 10) & 31), a);
            }
        }
    };
    auto zeroBins = [&]() {
        float4 z = {0.f, 0.f, 0.f, 0.f};
        for (int e = tid * 4; e < 64 * DBS; e += 1024) *(float4*)&dbuf[e] = z;
    };

    // ---- QK logits + dk_xyz ----
    {
        short8 aq = *(const short8*)&q_s[(w * 16 + l4) * 40 + quad * 8];
#pragma unroll
        for (int tt = 0; tt < 4; ++tt) {
            short8 bk = *(const short8*)&k_s[(tt * 16 + l4) * 40 + quad * 8];
            f32x4 r = {0.f, 0.f, 0.f, 0.f};
            r = __builtin_amdgcn_mfma_f32_16x16x32_bf16(aq, bk, r, 0, 0, 0);
            lg[tt][0] = r[0]; lg[tt][1] = r[1]; lg[tt][2] = r[2]; lg[tt][3] = r[3];
        }
    }
    tgemm(k_s, 8, 120);                  // dk_xyz
    __syncthreads();
    gatherX(true);                       // bias_k xyz
    stageTbl(krt + h * 32, 96, 96);
    __syncthreads();
    tgemm(k_s, 6, 96);                   // dk_rgb
    __syncthreads();
    gatherR(true);                       // bias_k rgb
    stageTbl(qxt + h * 32, 120, 128);
    __syncthreads();
    tgemm(q_s, 8, 120);                  // dq_xyz
    __syncthreads();
    gatherX(false);                      // bias_q xyz
    stageTbl(qrt + h * 32, 96, 96);
    __syncthreads();
    tgemm(q_s, 6, 96);                   // dq_rgb
    __syncthreads();
    gatherR(false);                      // bias_q rgb
    stageVtbl(vxt + h * 32, 120);        // tbl + cwf regions dead now
    stageVt();                           // k_s tail dead now
    __syncthreads();

    // ---- softmax ----
#pragma unroll
    for (int reg = 0; reg < 4; ++reg) {
        float m = fmaxf(fmaxf(lg[0][reg], lg[1][reg]), fmaxf(lg[2][reg], lg[3][reg]));
        m = fmaxf(m, __shfl_xor(m, 1));
        m = fmaxf(m, __shfl_xor(m, 2));
        m = fmaxf(m, __shfl_xor(m, 4));
        m = fmaxf(m, __shfl_xor(m, 8));
        float s = 0.f;
#pragma unroll
        for (int tt = 0; tt < 4; ++tt) { lg[tt][reg] = __expf(lg[tt][reg] - m); s += lg[tt][reg]; }
        s += __shfl_xor(s, 1); s += __shfl_xor(s, 2);
        s += __shfl_xor(s, 4); s += __shfl_xor(s, 8);
        float inv = 1.f / s;
#pragma unroll
        for (int tt = 0; tt < 4; ++tt) lg[tt][reg] *= inv;
    }
#pragma unroll
    for (int tt = 0; tt < 4; ++tt)
#pragma unroll
        for (int reg = 0; reg < 4; ++reg)
            attn_s[(w * 16 + quad * 4 + reg) * 72 + tt * 16 + l4] = f2bf(lg[tt][reg]);
    zeroBins();
    __syncthreads();

    // ---- scatter xyz bins + AV ----
    scatterX();
    f32x4 acc0 = {0.f, 0.f, 0.f, 0.f}, acc1 = {0.f, 0.f, 0.f, 0.f};
#pragma unroll
    for (int s = 0; s < 2; ++s) {
        short8 af = *(const short8*)&attn_s[(w * 16 + l4) * 72 + s * 32 + quad * 8];
        short8 b0 = *(const short8*)&v_t[l4 * 72 + s * 32 + quad * 8];
        short8 b1 = *(const short8*)&v_t[(16 + l4) * 72 + s * 32 + quad * 8];
        acc0 = __builtin_amdgcn_mfma_f32_16x16x32_bf16(af, b0, acc0, 0, 0, 0);
        acc1 = __builtin_amdgcn_mfma_f32_16x16x32_bf16(af, b1, acc1, 0, 0, 0);
    }
    __syncthreads();

    auto atgemm = [&](int Rlim) {
#pragma unroll
        for (int s = 0; s < 4; ++s) {
            int koff = s * 32 + quad * 8;
            short8 af = {0, 0, 0, 0, 0, 0, 0, 0};
            if (koff < Rlim) {
                const float* ap = &dbuf[(w * 16 + l4) * DBS + koff];
#pragma unroll
                for (int ii = 0; ii < 8; ++ii) af[ii] = (short)f2bf(ap[ii]);
            }
            short8 b0 = *(const short8*)&vtbl[l4 * 136 + koff];
            short8 b1 = *(const short8*)&vtbl[(16 + l4) * 136 + koff];
            acc0 = __builtin_amdgcn_mfma_f32_16x16x32_bf16(af, b0, acc0, 0, 0, 0);
            acc1 = __builtin_amdgcn_mfma_f32_16x16x32_bf16(af, b1, acc1, 0, 0, 0);
        }
    };
    atgemm(120);                         // value-bias xyz
    __syncthreads();
    zeroBins();
    stageVtbl(vrt + h * 32, 96);
    __syncthreads();
    scatterR();
    __syncthreads();
    atgemm(96);                          // value-bias rgb

    // ---- epilogue: bf16 ao[i][h*32+d] ----
    {
        ushort* op = aout + (size_t)(n * 64 + w * 16 + quad * 4) * 256 + h * 32;
#pragma unroll
        for (int reg = 0; reg < 4; ++reg) {
            op[reg * 256 + l4] = f2bf(acc0[reg]);
            op[reg * 256 + 16 + l4] = f2bf(acc1[reg]);
        }
    }
}

// ---------------------------------------------------------------------------
// Proj GEMM (bf16 MFMA): out = ao(bf16) @ proj_w(fp32, cast inline)^T + pb
// ---------------------------------------------------------------------------
__global__ __launch_bounds__(256) void k_proj(
    const ushort* __restrict__ A, const float* __restrict__ B,
    const float* __restrict__ bias, float* __restrict__ out)
{
    __shared__ __align__(16) ushort a_s[128 * 72];
    __shared__ __align__(16) ushort b_s[64 * 72];
    const int tid = threadIdx.x;
    const int m0 = blockIdx.y * 128;
    const int n0 = blockIdx.x * 64;
    const int w = tid >> 6, wm = w >> 1, wn = w & 1;
    const int l4 = tid & 15, quad = (tid >> 4) & 3;
    f32x4 acc[4][2];
#pragma unroll
    for (int mt = 0; mt < 4; ++mt)
#pragma unroll
        for (int nt = 0; nt < 2; ++nt) acc[mt][nt] = (f32x4){0.f, 0.f, 0.f, 0.f};

    for (int k0 = 0; k0 < 256; k0 += 64) {
#pragma unroll
        for (int l = 0; l < 4; ++l) {
            int e = tid + l * 256;
            int row = e >> 3, kq = e & 7;
            *(uint4*)&a_s[row * 72 + kq * 8] =
                *(const uint4*)(A + (size_t)(m0 + row) * 256 + k0 + kq * 8);
        }
#pragma unroll
        for (int l = 0; l < 2; ++l) {
            int e = tid + l * 256;
            int row = e >> 3, kq = e & 7;
            const float* bp = B + (size_t)(n0 + row) * 256 + k0 + kq * 8;
            float4 v0 = *(const float4*)bp, v1 = *(const float4*)(bp + 4);
            union { ushort u[8]; uint4 v; } pk;
            pk.u[0] = f2bf(v0.x); pk.u[1] = f2bf(v0.y); pk.u[2] = f2bf(v0.z); pk.u[3] = f2bf(v0.w);
            pk.u[4] = f2bf(v1.x); pk.u[5] = f2bf(v1.y); pk.u[6] = f2bf(v1.z); pk.u[7] = f2bf(v1.w);
            *(uint4*)&b_s[row * 72 + kq * 8] = pk.v;
        }
        __syncthreads();
#pragma unroll
        for (int kh = 0; kh < 2; ++kh) {
            short8 bf0 = *(const short8*)&b_s[(wn * 32 + l4) * 72 + kh * 32 + quad * 8];
            short8 bf1 = *(const short8*)&b_s[(wn * 32 + 16 + l4) * 72 + kh * 32 + quad * 8];
#pragma unroll
            for (int mt = 0; mt < 4; ++mt) {
                short8 af = *(const short8*)&a_s[(wm * 64 + mt * 16 + l4) * 72 + kh * 32 + quad * 8];
                acc[mt][0] = __builtin_amdgcn_mfma_f32_16x16x32_bf16(af, bf0, acc[mt][0], 0, 0, 0);
                acc[mt][1] = __builtin_amdgcn_mfma_f32_16x16x32_bf16(af, bf1, acc[mt][1], 0, 0, 0);
            }
        }
        __syncthreads();
    }
#pragma unroll
    for (int nt = 0; nt < 2; ++nt) {
        int c = n0 + wn * 32 + nt * 16 + l4;
        float bv = bias[c];
#pragma unroll
        for (int mt = 0; mt < 4; ++mt) {
            int mbase = m0 + wm * 64 + mt * 16 + quad * 4;
#pragma unroll
            for (int reg = 0; reg < 4; ++reg)
                out[(size_t)(mbase + reg) * 256 + c] = acc[mt][nt][reg] + bv;
        }
    }
}

extern "C" void kernel_launch(void* const* d_in, const int* in_sizes, int n_in,
                              void* d_out, int out_size, void* d_ws, size_t ws_size,
                              hipStream_t stream)
{
    const float* feats = (const float*)d_in[0];
    const float* nco   = (const float*)d_in[1];
    const float* qkvw  = (const float*)d_in[2];
    const float* qkvb  = (const float*)d_in[3];
    const float* qxt   = (const float*)d_in[4];
    const float* kxt   = (const float*)d_in[5];
    const float* vxt   = (const float*)d_in[6];
    const float* qrt   = (const float*)d_in[7];
    const float* krt   = (const float*)d_in[8];
    const float* vrt   = (const float*)d_in[9];
    const float* pw    = (const float*)d_in[10];
    const float* pb    = (const float*)d_in[11];
    float* out = (float*)d_out;

    ushort* qb  = (ushort*)d_ws;                       // [128][8][64][32] bf16
    ushort* kb  = qb + (size_t)2097152;
    ushort* vb  = kb + (size_t)2097152;
    ushort* aob = vb + (size_t)2097152;                // [8192][256] bf16

    k_qkv<<<dim3(12, 64), 256, 0, stream>>>(feats, qkvw, qkvb, qb, kb, vb);
    k_attn<<<dim3(1024), 256, 0, stream>>>(qb, kb, vb, nco, qxt, kxt, vxt, qrt, krt, vrt, aob);
    k_proj<<<dim3(4, 64), 256, 0, stream>>>(aob, pw, pb, out);
}

// Round 10
// 269.363 us; speedup vs baseline: 1.0603x; 1.0450x over previous
//
#include <hip/hip_runtime.h>

// DIM=256 H=8 HD=32 W=64 N=8192 nw=128
// xyz: T=40, off=20, hi=39, R=120 (pad 128) ; rgb: T=32, off=16, hi=31, R=96
// table element ((c*T+t)*8+h)*32+d == r*256 + h*32 + d, r=c*T+t

typedef __attribute__((ext_vector_type(8))) short short8;
typedef __attribute__((ext_vector_type(4))) float f32x4;

__device__ __forceinline__ unsigned short f2bf(float f) {
    union { float f; unsigned int u; } v; v.f = f;
    unsigned int r = v.u + 0x7FFFu + ((v.u >> 16) & 1u);
    return (unsigned short)(r >> 16);
}

// ---------------------------------------------------------------------------
// QKV GEMM (bf16 MFMA), fp32 inputs cast inline during staging.
// ---------------------------------------------------------------------------
__global__ __launch_bounds__(256) void k_qkv(
    const float* __restrict__ A, const float* __restrict__ B,
    const float* __restrict__ bias,
    ushort* __restrict__ qb, ushort* __restrict__ kb, ushort* __restrict__ vb)
{
    __shared__ __align__(16) ushort a_s[128 * 72];
    __shared__ __align__(16) ushort b_s[64 * 72];
    const int tid = threadIdx.x;
    const int m0 = blockIdx.y * 128;
    const int n0 = blockIdx.x * 64;
    const int w = tid >> 6, wm = w >> 1, wn = w & 1;
    const int l4 = tid & 15, quad = (tid >> 4) & 3;
    f32x4 acc[4][2];
#pragma unroll
    for (int mt = 0; mt < 4; ++mt)
#pragma unroll
        for (int nt = 0; nt < 2; ++nt) acc[mt][nt] = (f32x4){0.f, 0.f, 0.f, 0.f};

    for (int k0 = 0; k0 < 256; k0 += 64) {
#pragma unroll
        for (int l = 0; l < 4; ++l) {
            int e = tid + l * 256;
            int row = e >> 3, kq = e & 7;
            const float* ap = A + (size_t)(m0 + row) * 256 + k0 + kq * 8;
            float4 v0 = *(const float4*)ap, v1 = *(const float4*)(ap + 4);
            union { ushort u[8]; uint4 v; } pk;
            pk.u[0] = f2bf(v0.x); pk.u[1] = f2bf(v0.y); pk.u[2] = f2bf(v0.z); pk.u[3] = f2bf(v0.w);
            pk.u[4] = f2bf(v1.x); pk.u[5] = f2bf(v1.y); pk.u[6] = f2bf(v1.z); pk.u[7] = f2bf(v1.w);
            *(uint4*)&a_s[row * 72 + kq * 8] = pk.v;
        }
#pragma unroll
        for (int l = 0; l < 2; ++l) {
            int e = tid + l * 256;
            int row = e >> 3, kq = e & 7;
            const float* bp = B + (size_t)(n0 + row) * 256 + k0 + kq * 8;
            float4 v0 = *(const float4*)bp, v1 = *(const float4*)(bp + 4);
            union { ushort u[8]; uint4 v; } pk;
            pk.u[0] = f2bf(v0.x); pk.u[1] = f2bf(v0.y); pk.u[2] = f2bf(v0.z); pk.u[3] = f2bf(v0.w);
            pk.u[4] = f2bf(v1.x); pk.u[5] = f2bf(v1.y); pk.u[6] = f2bf(v1.z); pk.u[7] = f2bf(v1.w);
            *(uint4*)&b_s[row * 72 + kq * 8] = pk.v;
        }
        __syncthreads();
#pragma unroll
        for (int kh = 0; kh < 2; ++kh) {
            short8 bf0 = *(const short8*)&b_s[(wn * 32 + l4) * 72 + kh * 32 + quad * 8];
            short8 bf1 = *(const short8*)&b_s[(wn * 32 + 16 + l4) * 72 + kh * 32 + quad * 8];
#pragma unroll
            for (int mt = 0; mt < 4; ++mt) {
                short8 af = *(const short8*)&a_s[(wm * 64 + mt * 16 + l4) * 72 + kh * 32 + quad * 8];
                acc[mt][0] = __builtin_amdgcn_mfma_f32_16x16x32_bf16(af, bf0, acc[mt][0], 0, 0, 0);
                acc[mt][1] = __builtin_amdgcn_mfma_f32_16x16x32_bf16(af, bf1, acc[mt][1], 0, 0, 0);
            }
        }
        __syncthreads();
    }
#pragma unroll
    for (int nt = 0; nt < 2; ++nt) {
        int c = n0 + wn * 32 + nt * 16 + l4;
        float bv = bias[c];
        int s = c >> 8, rem = c & 255, h = rem >> 5, d = rem & 31;
        ushort* dst = (s == 0) ? qb : ((s == 1) ? kb : vb);
        float mul = (s == 0) ? 0.17677669529663687f : 1.0f;
#pragma unroll
        for (int mt = 0; mt < 4; ++mt) {
            int mbase = m0 + wm * 64 + mt * 16 + quad * 4;
#pragma unroll
            for (int reg = 0; reg < 4; ++reg) {
                int m = mbase + reg;
                int nw = m >> 6, ii = m & 63;
                dst[((size_t)((nw * 8 + h) * 64 + ii)) * 32 + d] = f2bf((acc[mt][nt][reg] + bv) * mul);
            }
        }
    }
}

// ---------------------------------------------------------------------------
// MFMA attention per (window, head). Round-7 phase structure.
// REGISTER BUDGET (round-9 post-mortem): gfx950 unified VGPR+AGPR file; this
// kernel's arch(172)+AGPR total exceeded 256 -> 1 wave/SIMD (occupancy 11.6%
// = ~4 waves/CU) — the invariant ~175 µs floor. Fix: __launch_bounds__(256,2)
// (total <= 256) PLUS pressure cuts so it fits without spill:
//   - no idx register arrays: packed indices recomputed at each of 6 use
//     sites from LDS cwf (dedicated region, alive whole kernel)
//   - staging processes 8 floats/unit (not 16)
// Spill tripwire: WRITE_SIZE >> 4 MB means it still doesn't fit.
// LDS: dbuf 31,232 + U 22,528 + cwf 1,536 = 55,296 B -> 2 blocks/CU.
// ---------------------------------------------------------------------------
#define DBS 122

__global__ __launch_bounds__(256, 2) void k_attn(
    const ushort* __restrict__ qb, const ushort* __restrict__ kb, const ushort* __restrict__ vb,
    const float* __restrict__ nco,
    const float* __restrict__ qxt, const float* __restrict__ kxt, const float* __restrict__ vxt,
    const float* __restrict__ qrt, const float* __restrict__ krt, const float* __restrict__ vrt,
    ushort* __restrict__ aout)
{
    __shared__ __align__(16) float dbuf[64 * DBS];
    __shared__ __align__(16) ushort U[11264];
    __shared__ __align__(16) float cwf[64 * 6];   // dedicated, alive all kernel
    // Phase A overlays:
    ushort* q_s  = U;              // [64][40]
    ushort* k_s  = U + 2560;       // [64][40]
    ushort* tbl  = U + 5120;       // [128][40]
    // Phase B overlays:
    ushort* attn_s = U;            // [64][72]
    ushort* v_t    = U + 4608;     // [32][72]
    ushort* vtbl   = U + 6912;     // [32][136]

    const int tid = threadIdx.x;
    const int n = blockIdx.x >> 3;
    const int h = blockIdx.x & 7;
    const int w = tid >> 6;
    const int l4 = tid & 15;
    const int quad = (tid >> 4) & 3;

    const size_t base = (size_t)((n * 8 + h) * 64) * 32;

    // ---- stage q, k, coords ----
    {
        int row = tid >> 2, part = tid & 3;
        *(uint4*)&q_s[row * 40 + part * 8] = *(const uint4*)(qb + base + tid * 8);
        *(uint4*)&k_s[row * 40 + part * 8] = *(const uint4*)(kb + base + tid * 8);
    }
    if (tid < 64) {
        const float* cp = nco + (size_t)(n * 64 + tid) * 6;
        cwf[tid * 6 + 0] = cp[0] * 4.f; cwf[tid * 6 + 1] = cp[1] * 4.f;
        cwf[tid * 6 + 2] = cp[2] * 4.f; cwf[tid * 6 + 3] = cp[3] * 8.f;
        cwf[tid * 6 + 4] = cp[4] * 8.f; cwf[tid * 6 + 5] = cp[5] * 8.f;
    }

    auto stageTbl = [&](const float* tbg, int R, int Rpad) {
        for (int e = tid; e < R * 4; e += 256) {
            int r = e >> 2, part = e & 3;
            const float* src = tbg + (size_t)r * 256 + part * 8;
            float4 f0 = *(const float4*)src, f1 = *(const float4*)(src + 4);
            union { ushort u[8]; uint4 v; } pk;
            pk.u[0] = f2bf(f0.x); pk.u[1] = f2bf(f0.y); pk.u[2] = f2bf(f0.z); pk.u[3] = f2bf(f0.w);
            pk.u[4] = f2bf(f1.x); pk.u[5] = f2bf(f1.y); pk.u[6] = f2bf(f1.z); pk.u[7] = f2bf(f1.w);
            *(uint4*)&tbl[r * 40 + part * 8] = pk.v;
        }
        for (int e = tid; e < (Rpad - R) * 40; e += 256) tbl[R * 40 + e] = 0;
    };
    auto stageVtbl = [&](const float* tbg, int R) {
        for (int e = tid; e < R * 4; e += 256) {
            int r = e >> 2, part = e & 3;
            const float* src = tbg + (size_t)r * 256 + part * 8;
            float4 f0 = *(const float4*)src, f1 = *(const float4*)(src + 4);
            int d0 = part * 8;
            vtbl[(d0 + 0) * 136 + r] = f2bf(f0.x);
            vtbl[(d0 + 1) * 136 + r] = f2bf(f0.y);
            vtbl[(d0 + 2) * 136 + r] = f2bf(f0.z);
            vtbl[(d0 + 3) * 136 + r] = f2bf(f0.w);
            vtbl[(d0 + 4) * 136 + r] = f2bf(f1.x);
            vtbl[(d0 + 5) * 136 + r] = f2bf(f1.y);
            vtbl[(d0 + 6) * 136 + r] = f2bf(f1.z);
            vtbl[(d0 + 7) * 136 + r] = f2bf(f1.w);
        }
        int span = 128 - R;
        for (int e = tid; e < 32 * span; e += 256) {
            int d = e / span, rr = e - d * span;
            vtbl[d * 136 + R + rr] = 0;
        }
    };
    auto stageVt = [&]() {
        int j = tid >> 2, d0 = (tid & 3) * 8;
        uint4 pk = *(const uint4*)(vb + base + tid * 8);
        const ushort* u = (const ushort*)&pk;
#pragma unroll
        for (int ii = 0; ii < 8; ++ii) v_t[(d0 + ii) * 72 + j] = u[ii];
    };

    auto tgemm = [&](const ushort* a_s, int NT, int maxc) {
        short8 af = *(const short8*)&a_s[(w * 16 + l4) * 40 + quad * 8];
        for (int tt = 0; tt < NT; ++tt) {
            short8 bf = *(const short8*)&tbl[(tt * 16 + l4) * 40 + quad * 8];
            f32x4 a = {0.f, 0.f, 0.f, 0.f};
            a = __builtin_amdgcn_mfma_f32_16x16x32_bf16(af, bf, a, 0, 0, 0);
            int col = tt * 16 + l4;
            int rb = w * 16 + quad * 4;
            if (col < maxc) {
                dbuf[(rb + 0) * DBS + col] = a[0];
                dbuf[(rb + 1) * DBS + col] = a[1];
                dbuf[(rb + 2) * DBS + col] = a[2];
                dbuf[(rb + 3) * DBS + col] = a[3];
            }
        }
    };

    stageTbl(kxt + h * 32, 120, 128);
    __syncthreads();

    float lg[4][4];   // [tt][reg]: row i = w*16+quad*4+reg, col j = tt*16+l4

    // Indices recomputed from cwf at every use site (no idx register arrays).
    auto gatherX = [&](bool useJ) {
#pragma unroll
        for (int tt = 0; tt < 4; ++tt) {
            int j = tt * 16 + l4;
            float cj0 = cwf[j * 6 + 0], cj1 = cwf[j * 6 + 1], cj2 = cwf[j * 6 + 2];
#pragma unroll
            for (int reg = 0; reg < 4; ++reg) {
                int i = w * 16 + quad * 4 + reg;
                int x0 = min(max((int)floorf(cwf[i * 6 + 0] - cj0) + 20, 0), 39);
                int x1 = min(max((int)floorf(cwf[i * 6 + 1] - cj1) + 20, 0), 39);
                int x2 = min(max((int)floorf(cwf[i * 6 + 2] - cj2) + 20, 0), 39);
                int b = (useJ ? j : i) * DBS;
                lg[tt][reg] += dbuf[b + x0] + dbuf[b + 40 + x1] + dbuf[b + 80 + x2];
            }
        }
    };
    auto gatherR = [&](bool useJ) {
#pragma unroll
        for (int tt = 0; tt < 4; ++tt) {
            int j = tt * 16 + l4;
            float cj3 = cwf[j * 6 + 3], cj4 = cwf[j * 6 + 4], cj5 = cwf[j * 6 + 5];
#pragma unroll
            for (int reg = 0; reg < 4; ++reg) {
                int i = w * 16 + quad * 4 + reg;
                int r0 = min(max((int)floorf(cwf[i * 6 + 3] - cj3) + 16, 0), 31);
                int r1 = min(max((int)floorf(cwf[i * 6 + 4] - cj4) + 16, 0), 31);
                int r2 = min(max((int)floorf(cwf[i * 6 + 5] - cj5) + 16, 0), 31);
                int b = (useJ ? j : i) * DBS;
                lg[tt][reg] += dbuf[b + r0] + dbuf[b + 32 + r1] + dbuf[b + 64 + r2];
            }
        }
    };
    auto scatterX = [&]() {
#pragma unroll
        for (int tt = 0; tt < 4; ++tt) {
            int j = tt * 16 + l4;
            float cj0 = cwf[j * 6 + 0], cj1 = cwf[j * 6 + 1], cj2 = cwf[j * 6 + 2];
#pragma unroll
            for (int reg = 0; reg < 4; ++reg) {
                int i = w * 16 + quad * 4 + reg;
                int x0 = min(max((int)floorf(cwf[i * 6 + 0] - cj0) + 20, 0), 39);
                int x1 = min(max((int)floorf(cwf[i * 6 + 1] - cj1) + 20, 0), 39);
                int x2 = min(max((int)floorf(cwf[i * 6 + 2] - cj2) + 20, 0), 39);
                float* bi = &dbuf[i * DBS];
                float a = lg[tt][reg];
                atomicAdd(bi + x0, a);
                atomicAdd(bi + 40 + x1, a);
                atomicAdd(bi + 80 + x2, a);
            }
        }
    };
    auto scatterR = [&]() {
#pragma unroll
        for (int tt = 0; tt < 4; ++tt) {
            int j = tt * 16 + l4;
            float cj3 = cwf[j * 6 + 3], cj4 = cwf[j * 6 + 4], cj5 = cwf[j * 6 + 5];
#pragma unroll
            for (int reg = 0; reg < 4; ++reg) {
                int i = w * 16 + quad * 4 + reg;
                int r0 = min(max((int)floorf(cwf[i * 6 + 3] - cj3) + 16, 0), 31);
                int r1 = min(max((int)floorf(cwf[i * 6 + 4] - cj4) + 16, 0), 31);
                int r2 = min(max((int)floorf(cwf[i * 6 + 5] - cj5) + 16, 0), 31);
                float* bi = &dbuf[i * DBS];
                float a = lg[tt][reg];
                atomicAdd(bi + r0, a);
                atomicAdd(bi + 32 + r1, a);
                atomicAdd(bi + 64 + r2, a);
            }
        }
    };
    auto zeroBins = [&]() {
        float4 z = {0.f, 0.f, 0.f, 0.f};
        for (int e = tid * 4; e < 64 * DBS; e += 1024) *(float4*)&dbuf[e] = z;
    };

    // ---- QK logits + dk_xyz ----
    {
        short8 aq = *(const short8*)&q_s[(w * 16 + l4) * 40 + quad * 8];
#pragma unroll
        for (int tt = 0; tt < 4; ++tt) {
            short8 bk = *(const short8*)&k_s[(tt * 16 + l4) * 40 + quad * 8];
            f32x4 r = {0.f, 0.f, 0.f, 0.f};
            r = __builtin_amdgcn_mfma_f32_16x16x32_bf16(aq, bk, r, 0, 0, 0);
            lg[tt][0] = r[0]; lg[tt][1] = r[1]; lg[tt][2] = r[2]; lg[tt][3] = r[3];
        }
    }
    tgemm(k_s, 8, 120);                  // dk_xyz
    __syncthreads();
    gatherX(true);                       // bias_k xyz
    stageTbl(krt + h * 32, 96, 96);
    __syncthreads();
    tgemm(k_s, 6, 96);                   // dk_rgb
    __syncthreads();
    gatherR(true);                       // bias_k rgb
    stageTbl(qxt + h * 32, 120, 128);
    __syncthreads();
    tgemm(q_s, 8, 120);                  // dq_xyz
    __syncthreads();
    gatherX(false);                      // bias_q xyz
    stageTbl(qrt + h * 32, 96, 96);
    __syncthreads();
    tgemm(q_s, 6, 96);                   // dq_rgb
    __syncthreads();
    gatherR(false);                      // bias_q rgb
    stageVtbl(vxt + h * 32, 120);        // tbl region dead now
    stageVt();                           // k_s tail dead now
    __syncthreads();

    // ---- softmax ----
#pragma unroll
    for (int reg = 0; reg < 4; ++reg) {
        float m = fmaxf(fmaxf(lg[0][reg], lg[1][reg]), fmaxf(lg[2][reg], lg[3][reg]));
        m = fmaxf(m, __shfl_xor(m, 1));
        m = fmaxf(m, __shfl_xor(m, 2));
        m = fmaxf(m, __shfl_xor(m, 4));
        m = fmaxf(m, __shfl_xor(m, 8));
        float s = 0.f;
#pragma unroll
        for (int tt = 0; tt < 4; ++tt) { lg[tt][reg] = __expf(lg[tt][reg] - m); s += lg[tt][reg]; }
        s += __shfl_xor(s, 1); s += __shfl_xor(s, 2);
        s += __shfl_xor(s, 4); s += __shfl_xor(s, 8);
        float inv = 1.f / s;
#pragma unroll
        for (int tt = 0; tt < 4; ++tt) lg[tt][reg] *= inv;
    }
#pragma unroll
    for (int tt = 0; tt < 4; ++tt)
#pragma unroll
        for (int reg = 0; reg < 4; ++reg)
            attn_s[(w * 16 + quad * 4 + reg) * 72 + tt * 16 + l4] = f2bf(lg[tt][reg]);
    zeroBins();
    __syncthreads();

    // ---- scatter xyz bins + AV ----
    scatterX();
    f32x4 acc0 = {0.f, 0.f, 0.f, 0.f}, acc1 = {0.f, 0.f, 0.f, 0.f};
#pragma unroll
    for (int s = 0; s < 2; ++s) {
        short8 af = *(const short8*)&attn_s[(w * 16 + l4) * 72 + s * 32 + quad * 8];
        short8 b0 = *(const short8*)&v_t[l4 * 72 + s * 32 + quad * 8];
        short8 b1 = *(const short8*)&v_t[(16 + l4) * 72 + s * 32 + quad * 8];
        acc0 = __builtin_amdgcn_mfma_f32_16x16x32_bf16(af, b0, acc0, 0, 0, 0);
        acc1 = __builtin_amdgcn_mfma_f32_16x16x32_bf16(af, b1, acc1, 0, 0, 0);
    }
    __syncthreads();

    auto atgemm = [&](int Rlim) {
#pragma unroll
        for (int s = 0; s < 4; ++s) {
            int koff = s * 32 + quad * 8;
            short8 af = {0, 0, 0, 0, 0, 0, 0, 0};
            if (koff < Rlim) {
                const float* ap = &dbuf[(w * 16 + l4) * DBS + koff];
#pragma unroll
                for (int ii = 0; ii < 8; ++ii) af[ii] = (short)f2bf(ap[ii]);
            }
            short8 b0 = *(const short8*)&vtbl[l4 * 136 + koff];
            short8 b1 = *(const short8*)&vtbl[(16 + l4) * 136 + koff];
            acc0 = __builtin_amdgcn_mfma_f32_16x16x32_bf16(af, b0, acc0, 0, 0, 0);
            acc1 = __builtin_amdgcn_mfma_f32_16x16x32_bf16(af, b1, acc1, 0, 0, 0);
        }
    };
    atgemm(120);                         // value-bias xyz
    __syncthreads();
    zeroBins();
    stageVtbl(vrt + h * 32, 96);
    __syncthreads();
    scatterR();
    __syncthreads();
    atgemm(96);                          // value-bias rgb

    // ---- epilogue: bf16 ao[i][h*32+d] ----
    {
        ushort* op = aout + (size_t)(n * 64 + w * 16 + quad * 4) * 256 + h * 32;
#pragma unroll
        for (int reg = 0; reg < 4; ++reg) {
            op[reg * 256 + l4] = f2bf(acc0[reg]);
            op[reg * 256 + 16 + l4] = f2bf(acc1[reg]);
        }
    }
}

// ---------------------------------------------------------------------------
// Proj GEMM (bf16 MFMA): out = ao(bf16) @ proj_w(fp32, cast inline)^T + pb
// ---------------------------------------------------------------------------
__global__ __launch_bounds__(256) void k_proj(
    const ushort* __restrict__ A, const float* __restrict__ B,
    const float* __restrict__ bias, float* __restrict__ out)
{
    __shared__ __align__(16) ushort a_s[128 * 72];
    __shared__ __align__(16) ushort b_s[64 * 72];
    const int tid = threadIdx.x;
    const int m0 = blockIdx.y * 128;
    const int n0 = blockIdx.x * 64;
    const int w = tid >> 6, wm = w >> 1, wn = w & 1;
    const int l4 = tid & 15, quad = (tid >> 4) & 3;
    f32x4 acc[4][2];
#pragma unroll
    for (int mt = 0; mt < 4; ++mt)
#pragma unroll
        for (int nt = 0; nt < 2; ++nt) acc[mt][nt] = (f32x4){0.f, 0.f, 0.f, 0.f};

    for (int k0 = 0; k0 < 256; k0 += 64) {
#pragma unroll
        for (int l = 0; l < 4; ++l) {
            int e = tid + l * 256;
            int row = e >> 3, kq = e & 7;
            *(uint4*)&a_s[row * 72 + kq * 8] =
                *(const uint4*)(A + (size_t)(m0 + row) * 256 + k0 + kq * 8);
        }
#pragma unroll
        for (int l = 0; l < 2; ++l) {
            int e = tid + l * 256;
            int row = e >> 3, kq = e & 7;
            const float* bp = B + (size_t)(n0 + row) * 256 + k0 + kq * 8;
            float4 v0 = *(const float4*)bp, v1 = *(const float4*)(bp + 4);
            union { ushort u[8]; uint4 v; } pk;
            pk.u[0] = f2bf(v0.x); pk.u[1] = f2bf(v0.y); pk.u[2] = f2bf(v0.z); pk.u[3] = f2bf(v0.w);
            pk.u[4] = f2bf(v1.x); pk.u[5] = f2bf(v1.y); pk.u[6] = f2bf(v1.z); pk.u[7] = f2bf(v1.w);
            *(uint4*)&b_s[row * 72 + kq * 8] = pk.v;
        }
        __syncthreads();
#pragma unroll
        for (int kh = 0; kh < 2; ++kh) {
            short8 bf0 = *(const short8*)&b_s[(wn * 32 + l4) * 72 + kh * 32 + quad * 8];
            short8 bf1 = *(const short8*)&b_s[(wn * 32 + 16 + l4) * 72 + kh * 32 + quad * 8];
#pragma unroll
            for (int mt = 0; mt < 4; ++mt) {
                short8 af = *(const short8*)&a_s[(wm * 64 + mt * 16 + l4) * 72 + kh * 32 + quad * 8];
                acc[mt][0] = __builtin_amdgcn_mfma_f32_16x16x32_bf16(af, bf0, acc[mt][0], 0, 0, 0);
                acc[mt][1] = __builtin_amdgcn_mfma_f32_16x16x32_bf16(af, bf1, acc[mt][1], 0, 0, 0);
            }
        }
        __syncthreads();
    }
#pragma unroll
    for (int nt = 0; nt < 2; ++nt) {
        int c = n0 + wn * 32 + nt * 16 + l4;
        float bv = bias[c];
#pragma unroll
        for (int mt = 0; mt < 4; ++mt) {
            int mbase = m0 + wm * 64 + mt * 16 + quad * 4;
#pragma unroll
            for (int reg = 0; reg < 4; ++reg)
                out[(size_t)(mbase + reg) * 256 + c] = acc[mt][nt][reg] + bv;
        }
    }
}

extern "C" void kernel_launch(void* const* d_in, const int* in_sizes, int n_in,
                              void* d_out, int out_size, void* d_ws, size_t ws_size,
                              hipStream_t stream)
{
    const float* feats = (const float*)d_in[0];
    const float* nco   = (const float*)d_in[1];
    const float* qkvw  = (const float*)d_in[2];
    const float* qkvb  = (const float*)d_in[3];
    const float* qxt   = (const float*)d_in[4];
    const float* kxt   = (const float*)d_in[5];
    const float* vxt   = (const float*)d_in[6];
    const float* qrt   = (const float*)d_in[7];
    const float* krt   = (const float*)d_in[8];
    const float* vrt   = (const float*)d_in[9];
    const float* pw    = (const float*)d_in[10];
    const float* pb    = (const float*)d_in[11];
    float* out = (float*)d_out;

    ushort* qb  = (ushort*)d_ws;                       // [128][8][64][32] bf16
    ushort* kb  = qb + (size_t)2097152;
    ushort* vb  = kb + (size_t)2097152;
    ushort* aob = vb + (size_t)2097152;                // [8192][256] bf16

    k_qkv<<<dim3(12, 64), 256, 0, stream>>>(feats, qkvw, qkvb, qb, kb, vb);
    k_attn<<<dim3(1024), 256, 0, stream>>>(qb, kb, vb, nco, qxt, kxt, vxt, qrt, krt, vrt, aob);
    k_proj<<<dim3(4, 64), 256, 0, stream>>>(aob, pw, pb, out);
}